// Round 8
// baseline (262.520 us; speedup 1.0000x reference)
//
#include <hip/hip_runtime.h>

typedef unsigned short u16;
typedef unsigned int u32;
typedef __bf16 bf16x8 __attribute__((ext_vector_type(8)));
typedef float f32x4 __attribute__((ext_vector_type(4)));
typedef u32 u32x4 __attribute__((ext_vector_type(4)));

#define CIN 256
#define COUT_ 256
#define HW 56
#define LIMG 3136          // 56*56
#define XIMG (CIN * LIMG)  // elems per image
#define CDIM 2304          // 256*9
#define NSTEP 36           // 2304 / 64
#define GRID 784           // (16*3136/128) M-tiles * 2 N-tiles

// ---------------------------------------------------------------------------
// Weight quant: w (COUT, CDIM) -> wq[o][k'] bf16, k' = k ^ ((o&7)<<3)
// (pre-swizzled: GEMM stages with linear global_load_lds, reads with same XOR)
// ---------------------------------------------------------------------------
__global__ void quant_w_kernel(const float* __restrict__ w, u16* __restrict__ wq) {
    const int kb = blockIdx.x % 72;
    const int ob = blockIdx.x / 72;
    const int k0 = kb * 32, o0 = ob * 32;
    const int t = threadIdx.x;        // 64 threads
    float v[16];
    float mx = 0.f;
#pragma unroll
    for (int i = 0; i < 16; ++i) {
        const int e = i * 64 + t;
        const int oo = e >> 5, cc = e & 31;
        const float val = w[(o0 + oo) * CDIM + k0 + cc];
        v[i] = val;
        mx = fmaxf(mx, fabsf(val));
    }
#pragma unroll
    for (int d = 1; d < 64; d <<= 1) mx = fmaxf(mx, __shfl_xor(mx, d, 64));
    const float scale = mx > 0.f ? mx * (1.f / 127.f) : 1.f;
    const float inv   = mx > 0.f ? 127.f / mx : 1.f;
#pragma unroll
    for (int i = 0; i < 16; ++i) {
        const int e = i * 64 + t;
        const int oo = e >> 5, cc = e & 31;
        const int o = o0 + oo, k = k0 + cc;
        const float q = rintf(v[i] * inv) * scale;
        const u32 b = __float_as_uint(q) + 0x7fffu + ((__float_as_uint(q) >> 16) & 1u);
        wq[o * CDIM + (k ^ ((o & 7) << 3))] = (u16)(b >> 16);
    }
}

// ---------------------------------------------------------------------------
// Fused implicit-GEMM conv. BM=128, BN=128, BK=64. 256 thr = 4 waves (2x2),
// wave tile 64x64. Thread-local (1,32) quant (thread r=tid&127, half h=wn).
// Rotating 9-entry clamped-offset/mask register files (period of k mod 9).
// 2 raw barriers/step, counted vmcnt keeps 32 gathers in flight.
// ---------------------------------------------------------------------------
__global__ __launch_bounds__(256, 3)
void conv_gemm_kernel(const float* __restrict__ x, const u16* __restrict__ wq,
                      const float* __restrict__ bias, float* __restrict__ out) {
    __shared__ __align__(16) u16 Bs[128 * 64];   // 16 KB [col][slot^(col&7)]
    __shared__ __align__(16) u16 As[128 * 64];   // 16 KB [row][slot^(row&7)]

    const int tid  = threadIdx.x;
    const int lane = tid & 63;
    const int wid  = __builtin_amdgcn_readfirstlane(tid >> 6);  // 0..3
    const int wm   = wid & 1;
    const int wn   = wid >> 1;
    const int h    = wn;             // k-half this thread stages (r = tid&127)

    // XCD-aware swizzle (784 = 8*98, bijective), then split M x N
    const int bid = (blockIdx.x & 7) * 98 + (blockIdx.x >> 3);
    const int mt = bid >> 1, nt = bid & 1;
    const int m0 = mt * 128, n0 = nt * 128;

    const int r = wm * 64 + lane;    // staging row (== tid & 127)
    const int m = m0 + r;
    const int img = m / 3136;
    const int l   = m - img * 3136;
    const int oh  = l / HW, ow = l - (l / HW) * HW;

    // 9-bit validity over kernel positions p = kh*3+kw
    u32 pb = 0;
#pragma unroll
    for (int p = 0; p < 9; ++p) {
        const int kh = p / 3, kw = p - (p / 3) * 3;
        const int ih = oh + kh - 1, iw = ow + kw - 1;
        const u32 ok = (ih >= 0 && ih < HW && iw >= 0 && iw < HW) ? 1u : 0u;
        pb |= ok << p;
    }

    // rotating register files: roff[q]/rmb[q] correspond to p=(k0+q)%9.
    // k advances 64 = 9*7+1 per step -> rotate by 1 each step.
    u32 roff[9], rmb[9];
#pragma unroll
    for (int q = 0; q < 9; ++q) {
        const int p = (h * 32 + q) % 9;          // scalar
        const int kh = p / 3;
        const int dsp = (kh - 1) * HW + (p - kh * 3) - 1;
        int e = l + dsp;
        e = min(max(e, 0), LIMG - 1);            // fault-free clamp
        roff[q] = (u32)(img * XIMG + e) * 4u;    // byte offset into x
        rmb[q]  = 0u - ((pb >> p) & 1u);         // all-ones if valid
    }

    f32x4 acc[4][4];
#pragma unroll
    for (int mi = 0; mi < 4; ++mi)
#pragma unroll
        for (int n = 0; n < 4; ++n)
            acc[mi][n] = (f32x4){0.f, 0.f, 0.f, 0.f};

    float va[32];

    // issue 32 gathers for step t (normal loads; compiler-tracked waits)
    auto gather_issue = [&](int t) {
        const int k0 = t * 64 + h * 32;          // scalar
#pragma unroll
        for (int j = 0; j < 32; ++j) {
            const u32 soff = (u32)(((k0 + j) / 9) * (LIMG * 4));  // SALU
            va[j] = *(const float*)((const char*)x + (roff[j % 9] + soff));
        }
        // rotate roff by 1 for next step
        u32 t0 = roff[0];
#pragma unroll
        for (int q = 0; q < 8; ++q) roff[q] = roff[q + 1];
        roff[8] = t0;
    };

    gather_issue(0);                             // prologue

#pragma unroll 1
    for (int t = 0; t < NSTEP; ++t) {
        // ---- (1) stage B tile (linear gload_lds; source pre-swizzled) ----
#pragma unroll
        for (int i = 0; i < 4; ++i) {
            const int colt = n0 + i * 32 + (tid >> 3);
            const u16* g = wq + (size_t)colt * CDIM + t * 64 + (tid & 7) * 8;
            u16* lp = &Bs[0] + i * 2048 + tid * 8;
            __builtin_amdgcn_global_load_lds(
                (const __attribute__((address_space(1))) void*)g,
                (__attribute__((address_space(3))) void*)lp, 16, 0, 0);
        }
        asm volatile("" ::: "memory");           // pin: gloads precede gathers
        __builtin_amdgcn_sched_barrier(0);

        // ---- (2) consume va(t): mask, max, quantize, write As ----
#pragma unroll
        for (int j = 0; j < 32; ++j)
            va[j] = __uint_as_float(__float_as_uint(va[j]) & rmb[j % 9]);
        // rotate rmb for next step
        {
            u32 t0 = rmb[0];
#pragma unroll
            for (int q = 0; q < 8; ++q) rmb[q] = rmb[q + 1];
            rmb[8] = t0;
        }
        float t16[16];
#pragma unroll
        for (int j = 0; j < 16; ++j) t16[j] = fmaxf(fabsf(va[j]), fabsf(va[j + 16]));
        float m8[8];
#pragma unroll
        for (int j = 0; j < 8; ++j) m8[j] = fmaxf(t16[j], t16[j + 8]);
        const float ma = fmaxf(fmaxf(m8[0], m8[1]), m8[2]);
        const float mb = fmaxf(fmaxf(m8[3], m8[4]), m8[5]);
        const float mc = fmaxf(m8[6], m8[7]);
        const float mx = fmaxf(fmaxf(ma, mb), mc);

        const float inv   = mx > 0.f ? 127.f * __builtin_amdgcn_rcpf(mx) : 0.f;
        const float scale = mx * (1.f / 127.f);

        union { __bf16 hh[32]; u32x4 v4[4]; } pk;
#pragma unroll
        for (int j = 0; j < 32; ++j)
            pk.hh[j] = (__bf16)(rintf(va[j] * inv) * scale);
#pragma unroll
        for (int w = 0; w < 4; ++w) {
            const int s = h * 4 + w;
            *(u32x4*)&As[r * 64 + ((s ^ (r & 7)) << 3)] = pk.v4[w];
        }
        asm volatile("" ::: "memory");
        __builtin_amdgcn_sched_barrier(0);

        // ---- (3) issue gathers for t+1; counted drain; barrier ----
        if (t < NSTEP - 1) {
            gather_issue(t + 1);
            // outstanding: 4 gloads (old) + 32 gathers (new) -> drain gloads
            asm volatile("s_waitcnt lgkmcnt(0) vmcnt(32)" ::: "memory");
        } else {
            asm volatile("s_waitcnt lgkmcnt(0) vmcnt(0)" ::: "memory");
        }
        __builtin_amdgcn_sched_barrier(0);
        __builtin_amdgcn_s_barrier();            // As/Bs ready (cross-wave)
        asm volatile("" ::: "memory");
        __builtin_amdgcn_sched_barrier(0);

        // ---- (4) MFMA: wave computes 64 rows x 64 cols ----
        const int arow_b = wm * 64 + (lane & 15);
        const int bcol_b = wn * 64 + (lane & 15);
        const int sl = lane >> 4;
        __builtin_amdgcn_s_setprio(1);
#pragma unroll
        for (int kk = 0; kk < 2; ++kk) {
            const int s = kk * 4 + sl;
            bf16x8 a[4], b[4];
#pragma unroll
            for (int mi = 0; mi < 4; ++mi) {
                const int ar = arow_b + mi * 16;
                a[mi] = *(const bf16x8*)&As[ar * 64 + ((s ^ (ar & 7)) << 3)];
            }
#pragma unroll
            for (int n = 0; n < 4; ++n) {
                const int cl = bcol_b + n * 16;
                b[n] = *(const bf16x8*)&Bs[cl * 64 + ((s ^ (cl & 7)) << 3)];
            }
#pragma unroll
            for (int n = 0; n < 4; ++n)
#pragma unroll
                for (int mi = 0; mi < 4; ++mi)
                    acc[mi][n] = __builtin_amdgcn_mfma_f32_16x16x32_bf16(a[mi], b[n], acc[mi][n], 0, 0, 0);
        }
        __builtin_amdgcn_s_setprio(0);
        asm volatile("" ::: "memory");
        __builtin_amdgcn_sched_barrier(0);
        __builtin_amdgcn_s_barrier();            // MFMA done: As/Bs reusable
        asm volatile("" ::: "memory");
        __builtin_amdgcn_sched_barrier(0);
    }

    // ---- epilogue: bias + store NCHW ----
    const int si    = __builtin_amdgcn_readfirstlane(m0 / 3136);
    const int l0    = m0 - si * 3136;
    const bool split = l0 > 3136 - 128;          // tile crosses image boundary
    const int rb = wm * 64 + ((lane >> 4) << 2);
#pragma unroll
    for (int n = 0; n < 4; ++n) {
        const int col = n0 + wn * 64 + n * 16 + (lane & 15);
        const float bz = bias[col];
#pragma unroll
        for (int mi = 0; mi < 4; ++mi) {
            f32x4 a = acc[mi][n];
            a[0] += bz; a[1] += bz; a[2] += bz; a[3] += bz;
            const int row = rb + mi * 16;
            if (!split) {
                *(f32x4*)&out[((size_t)(si * COUT_ + col)) * LIMG + l0 + row] = a;
            } else {
#pragma unroll
                for (int j = 0; j < 4; ++j) {
                    const int mm = m0 + row + j;
                    const int ig = mm / 3136;
                    const int ll = mm - ig * 3136;
                    out[((size_t)(ig * COUT_ + col)) * LIMG + ll] = a[j];
                }
            }
        }
    }
}

extern "C" void kernel_launch(void* const* d_in, const int* in_sizes, int n_in,
                              void* d_out, int out_size, void* d_ws, size_t ws_size,
                              hipStream_t stream) {
    const float* x    = (const float*)d_in[0];
    const float* w    = (const float*)d_in[1];
    const float* bias = (const float*)d_in[2];
    float* out = (float*)d_out;
    u16* wq = (u16*)d_ws;   // 2304*256*2 B = 1.18 MB

    quant_w_kernel<<<576, 64, 0, stream>>>(w, wq);
    conv_gemm_kernel<<<GRID, 256, 0, stream>>>(x, wq, bias, out);
}